// Round 3
// baseline (543.898 us; speedup 1.0000x reference)
//
#include <hip/hip_runtime.h>
#include <hip/hip_bf16.h>
#include <cstdint>

typedef __attribute__((ext_vector_type(8))) short short8;
typedef __attribute__((ext_vector_type(4))) float floatx4;

__device__ __forceinline__ float tanh_fast(float x) {
    float e = __expf(2.0f * x);                            // v_exp_f32 path
    return 1.0f - 2.0f * __builtin_amdgcn_rcpf(e + 1.0f);  // saturates to +-1
}

__device__ __forceinline__ unsigned int bf16_bits(float f) {
    __hip_bfloat16 h = __float2bfloat16(f);   // RNE
    return (unsigned int)*reinterpret_cast<unsigned short*>(&h);
}
__device__ __forceinline__ unsigned int pack2(float lo, float hi) {
    return bf16_bits(lo) | (bf16_bits(hi) << 16);
}

// LDS tiles: 128 rows x 64 k (bf16), row stride 72 shorts (144 B pad).
// ds_write_b64 staging: 4 lanes per 8B span  = wave64 floor (conflict-free).
// ds_read_b128 frags:   8 lanes per 16B span = wave64 floor (conflict-free).
#define LDS_STRIDE 72

// ---------------------------------------------------------------------------
// K1: out[0:pivot] = tanh(x @ W^T + b)   (f32 in, bf16 MFMA, f32 out)
// ---------------------------------------------------------------------------
__global__ __launch_bounds__(256) void k1_gemm_tanh(
    const float* __restrict__ X,
    const float* __restrict__ W,
    const float* __restrict__ Bv,
    float* __restrict__ out,
    int K)
{
    __shared__ __align__(16) short As[128 * LDS_STRIDE];
    __shared__ __align__(16) short Bs[128 * LDS_STRIDE];

    const int tid  = threadIdx.x;
    const int lane = tid & 63;
    const int wave = tid >> 6;
    const int wm = wave & 1, wn = wave >> 1;

    const int row0 = blockIdx.y * 128;
    const int col0 = blockIdx.x * 128;

    const int l15  = lane & 15;
    const int quad = lane >> 4;
    const int a_base = (wm * 64 + l15) * LDS_STRIDE;
    const int b_base = (wn * 64 + l15) * LDS_STRIDE;

    floatx4 acc[4][4];
#pragma unroll
    for (int a = 0; a < 4; ++a)
#pragma unroll
        for (int b = 0; b < 4; ++b) acc[a][b] = (floatx4){0.f, 0.f, 0.f, 0.f};

    for (int k0 = 0; k0 < K; k0 += 64) {
        __syncthreads();
#pragma unroll
        for (int i = 0; i < 8; ++i) {
            const int g = i * 256 + tid;
            const int r = g >> 4, c = g & 15;      // 128 rows x 16 float4-cols
            const float4 va = *(const float4*)(X + (size_t)(row0 + r) * K + k0 + c * 4);
            const float4 vb = *(const float4*)(W + (size_t)(col0 + r) * K + k0 + c * 4);
            uint2 ea, eb;
            ea.x = pack2(va.x, va.y); ea.y = pack2(va.z, va.w);
            eb.x = pack2(vb.x, vb.y); eb.y = pack2(vb.z, vb.w);
            *(uint2*)&As[r * LDS_STRIDE + c * 4] = ea;
            *(uint2*)&Bs[r * LDS_STRIDE + c * 4] = eb;
        }
        __syncthreads();
#pragma unroll
        for (int ki = 0; ki < 2; ++ki) {
            const int kx = ki * 32 + quad * 8;
            short8 af[4], bf[4];
#pragma unroll
            for (int s = 0; s < 4; ++s)
                af[s] = *(const short8*)&As[a_base + s * 16 * LDS_STRIDE + kx];
#pragma unroll
            for (int s = 0; s < 4; ++s)
                bf[s] = *(const short8*)&Bs[b_base + s * 16 * LDS_STRIDE + kx];
#pragma unroll
            for (int a = 0; a < 4; ++a)
#pragma unroll
                for (int b = 0; b < 4; ++b)
                    acc[a][b] = __builtin_amdgcn_mfma_f32_16x16x32_bf16(
                        af[a], bf[b], acc[a][b], 0, 0, 0);
        }
    }

    float bv[4];
#pragma unroll
    for (int b = 0; b < 4; ++b)
        bv[b] = Bv[col0 + wn * 64 + b * 16 + l15];

#pragma unroll
    for (int a = 0; a < 4; ++a) {
        const int rbase = row0 + wm * 64 + a * 16 + quad * 4;
#pragma unroll
        for (int b = 0; b < 4; ++b) {
            const int n = col0 + wn * 64 + b * 16 + l15;
#pragma unroll
            for (int r = 0; r < 4; ++r)
                out[(size_t)(rbase + r) * 1024 + n] = tanh_fast(acc[a][b][r] + bv[b]);
        }
    }
}

// ---------------------------------------------------------------------------
// K2: C2 = M @ W^T,  M[2p+kk, j] = G[p][2j+kk]  (de-interleave at staging)
// out[pivot + 2p + (i>=512)][(2i+kk)%1024] = (1 - h[p,i]^2) * C2[2p+kk, i]
// ---------------------------------------------------------------------------
__global__ __launch_bounds__(256) void k2_gemm_jac(
    const float* __restrict__ G,      // x_Jx + pivot*1024, rows of 2048 floats
    const float* __restrict__ W,
    const float* __restrict__ Hout,   // hAx (f32) = out rows [0, pivot)
    float* __restrict__ out2,         // out + pivot*1024
    int K)
{
    __shared__ __align__(16) short As[128 * LDS_STRIDE];
    __shared__ __align__(16) short Bs[128 * LDS_STRIDE];

    const int tid  = threadIdx.x;
    const int lane = tid & 63;
    const int wave = tid >> 6;
    const int wm = wave & 1, wn = wave >> 1;

    const int r0   = blockIdx.y * 128;    // M-row base (r = 2p+kk)
    const int p0   = r0 >> 1;
    const int col0 = blockIdx.x * 128;

    const int l15  = lane & 15;
    const int quad = lane >> 4;
    const int a_base = (wm * 64 + l15) * LDS_STRIDE;
    const int b_base = (wn * 64 + l15) * LDS_STRIDE;

    floatx4 acc[4][4];
#pragma unroll
    for (int a = 0; a < 4; ++a)
#pragma unroll
        for (int b = 0; b < 4; ++b) acc[a][b] = (floatx4){0.f, 0.f, 0.f, 0.f};

    for (int k0 = 0; k0 < K; k0 += 64) {
        __syncthreads();
        // B: W tile, same as K1
#pragma unroll
        for (int i = 0; i < 8; ++i) {
            const int g = i * 256 + tid;
            const int r = g >> 4, c = g & 15;
            const float4 vb = *(const float4*)(W + (size_t)(col0 + r) * K + k0 + c * 4);
            uint2 eb;
            eb.x = pack2(vb.x, vb.y); eb.y = pack2(vb.z, vb.w);
            *(uint2*)&Bs[r * LDS_STRIDE + c * 4] = eb;
        }
        // A: 64 pair-rows x 16 chunks of 8 floats (=4 channels x 2 jac-cols)
#pragma unroll
        for (int i = 0; i < 4; ++i) {
            const int g = i * 256 + tid;
            const int q = g >> 4, d = g & 15;   // q: pair-row 0..63, d: chunk
            const float* src = G + (size_t)(p0 + q) * 2048 + 2 * k0 + d * 8;
            const float4 u0 = *(const float4*)src;        // [j0k0 j0k1 j1k0 j1k1]
            const float4 u1 = *(const float4*)(src + 4);  // [j2k0 j2k1 j3k0 j3k1]
            uint2 E, O;
            E.x = pack2(u0.x, u0.z); E.y = pack2(u1.x, u1.z);   // kk=0 -> row 2q
            O.x = pack2(u0.y, u0.w); O.y = pack2(u1.y, u1.w);   // kk=1 -> row 2q+1
            *(uint2*)&As[(2 * q)     * LDS_STRIDE + d * 4] = E;
            *(uint2*)&As[(2 * q + 1) * LDS_STRIDE + d * 4] = O;
        }
        __syncthreads();
#pragma unroll
        for (int ki = 0; ki < 2; ++ki) {
            const int kx = ki * 32 + quad * 8;
            short8 af[4], bf[4];
#pragma unroll
            for (int s = 0; s < 4; ++s)
                af[s] = *(const short8*)&As[a_base + s * 16 * LDS_STRIDE + kx];
#pragma unroll
            for (int s = 0; s < 4; ++s)
                bf[s] = *(const short8*)&Bs[b_base + s * 16 * LDS_STRIDE + kx];
#pragma unroll
            for (int a = 0; a < 4; ++a)
#pragma unroll
                for (int b = 0; b < 4; ++b)
                    acc[a][b] = __builtin_amdgcn_mfma_f32_16x16x32_bf16(
                        af[a], bf[b], acc[a][b], 0, 0, 0);
        }
    }

    // epilogue: acc regs (0,1)/(2,3) are M-rows (2p, 2p+1) -> one float2 store
#pragma unroll
    for (int a = 0; a < 4; ++a) {
        const int rb = r0 + wm * 64 + a * 16 + quad * 4;   // even
#pragma unroll
        for (int b = 0; b < 4; ++b) {
            const int i = col0 + wn * 64 + b * 16 + l15;
            const int shift = (i >= 512) ? 1 : 0;
            const int ccol = 2 * i - shift * 1024;
#pragma unroll
            for (int pr = 0; pr < 2; ++pr) {
                const int re = rb + pr * 2;                // even row = 2p
                const int p  = re >> 1;
                const float h  = Hout[(size_t)p * 1024 + i];
                const float hp = 1.0f - h * h;
                float2 st;
                st.x = hp * acc[a][b][pr * 2];             // kk=0 -> col 2i
                st.y = hp * acc[a][b][pr * 2 + 1];         // kk=1 -> col 2i+1
                *(float2*)&out2[(size_t)(re + shift) * 1024 + ccol] = st;
            }
        }
    }
}

extern "C" void kernel_launch(void* const* d_in, const int* in_sizes, int n_in,
                              void* d_out, int out_size, void* d_ws, size_t ws_size,
                              hipStream_t stream) {
    const float* xJx = (const float*)d_in[0];
    const float* W   = (const float*)d_in[1];
    const float* bv  = (const float*)d_in[2];
    float* out = (float*)d_out;

    const int C     = 1024;
    const int rows3 = in_sizes[0] / C;   // 3*pivot
    const int pivot = rows3 / 3;         // 16384

    dim3 blk(256);
    dim3 g1(C / 128, pivot / 128);       // 8 x 128
    k1_gemm_tanh<<<g1, blk, 0, stream>>>(xJx, W, bv, out, C);

    dim3 g2(C / 128, (2 * pivot) / 128); // 8 x 256
    k2_gemm_jac<<<g2, blk, 0, stream>>>(xJx + (size_t)pivot * C, W, out,
                                        out + (size_t)pivot * C, C);
}